// Round 4
// baseline (132.749 us; speedup 1.0000x reference)
//
#include <hip/hip_runtime.h>

#define N_TOTAL 16384
#define HALF    8192
#define FEAT    128
#define MARGIN  0.3f
#define NBINS   1024   // NUM_IDS=1000 <= 1024

typedef __attribute__((ext_vector_type(8))) short  short8v;   // 8 x bf16 (4 VGPRs)
typedef __attribute__((ext_vector_type(4))) float  float4v;   // 4 x f32 acc

__device__ __forceinline__ unsigned short f32_to_bf16_rne(float f) {
    unsigned u = __float_as_uint(f);
    u += 0x7FFFu + ((u >> 16) & 1u);
    return (unsigned short)(u >> 16);
}

// ---------------------------------------------------------------------------
// sort_init: single block. LDS histogram of labels per half + scan -> cursor
// (global bucket starts). Also zeroes accF/accI/ticket. Replaces
// memset+hist+scan (3 dispatches -> 1).
// ---------------------------------------------------------------------------
__global__ __launch_bounds__(1024) void sort_init_kernel(
        const int* __restrict__ targets, int* __restrict__ cursor,
        int* __restrict__ accs /* [accF, accI, ticket] */) {
    __shared__ int lhist[2 * NBINS];
    const int t = threadIdx.x;
    lhist[t] = 0; lhist[NBINS + t] = 0;
    __syncthreads();
    #pragma unroll
    for (int k = 0; k < 16; ++k) {
        int i = k * 1024 + t;                       // 0..16383
        int h = i >> 13;
        atomicAdd(&lhist[(h << 10) + targets[i]], 1);
    }
    __syncthreads();
    const int lane = t & 63, wave = t >> 6;         // 16 waves
    int x0 = lhist[t], x1 = lhist[NBINS + t];
    const int o0 = x0, o1 = x1;
    #pragma unroll
    for (int m = 1; m < 64; m <<= 1) {              // inclusive wave scan
        int v0 = __shfl_up(x0, m, 64);
        int v1 = __shfl_up(x1, m, 64);
        if (lane >= m) { x0 += v0; x1 += v1; }
    }
    __shared__ int wsum[32];
    if (lane == 63) { wsum[wave] = x0; wsum[16 + wave] = x1; }
    __syncthreads();
    if (t == 0) {
        int s = 0;
        for (int w = 0; w < 16; ++w)  { int v = wsum[w]; wsum[w] = s; s += v; }
        s = 0;
        for (int w = 16; w < 32; ++w) { int v = wsum[w]; wsum[w] = s; s += v; }
        accs[0] = 0; accs[1] = 0; accs[2] = 0;
    }
    __syncthreads();
    cursor[t]         = x0 - o0 + wsum[wave];       // exclusive prefix (bucket start)
    cursor[NBINS + t] = x1 - o1 + wsum[16 + wave];
}

// ---------------------------------------------------------------------------
// prep: one wave per ORIGINAL row. Claims sorted slot via atomicAdd(cursor),
// converts fp32->bf16, computes bf16 row norm, writes Xb/sq/labs/sentinels
// at the sorted position. (scatter fused in; perm eliminated.)
// ---------------------------------------------------------------------------
__global__ __launch_bounds__(256) void prep_kernel(
        const float* __restrict__ X, const int* __restrict__ targets,
        int* __restrict__ cursor,
        unsigned* __restrict__ Xb, float* __restrict__ sq, int* __restrict__ labs,
        int* __restrict__ maxpos, int* __restrict__ minneg) {
    const int wave = threadIdx.x >> 6, lane = threadIdx.x & 63;
    const int src = blockIdx.x * 4 + wave;          // original row
    const int h   = src >> 13;
    const int lbl = targets[src];
    int dst;
    if (lane == 0)
        dst = (h << 13) + atomicAdd(&cursor[(h << 10) + lbl], 1);
    dst = __shfl(dst, 0, 64);
    const float2 xv = ((const float2*)(X + (size_t)src * FEAT))[lane];
    unsigned short h0 = f32_to_bf16_rne(xv.x);
    unsigned short h1 = f32_to_bf16_rne(xv.y);
    Xb[dst * 64 + lane] = (unsigned)h0 | ((unsigned)h1 << 16);
    float x0 = __uint_as_float((unsigned)h0 << 16);
    float x1 = __uint_as_float((unsigned)h1 << 16);
    float p = x0 * x0 + x1 * x1;
    #pragma unroll
    for (int m = 1; m < 64; m <<= 1) p += __shfl_xor(p, m, 64);
    if (lane == 0) {
        sq[dst]     = p;
        labs[dst]   = lbl;
        maxpos[dst] = (int)0xFF800000u;   // -inf
        minneg[dst] = 0x7F800000;         // +inf
    }
}

// ---------------------------------------------------------------------------
// main: 128x128 tile, 512 threads (8 waves x 32x64 quadrant) -> 2 blocks/CU
// = 4 waves/SIMD (2x the old occupancy). Fast path when label ranges of
// A-rows and B-cols are disjoint (all pairs negative).
// ---------------------------------------------------------------------------
__global__ __launch_bounds__(512, 4) void cross_kernel(
        const unsigned short* __restrict__ Xb, const float* __restrict__ sq,
        const int* __restrict__ labs,
        int* __restrict__ maxpos, int* __restrict__ minneg) {
    __shared__ unsigned short As[128 * 128];
    __shared__ unsigned short Bs[128 * 128];
    const int bm = blockIdx.x, bn = blockIdx.y;
    const int t  = threadIdx.x;

    const unsigned short* Ag = Xb + (size_t)bm * 128 * FEAT;
    const unsigned short* Bg = Xb + (size_t)(HALF + bn * 128) * FEAT;
    #pragma unroll
    for (int p = 0; p < 4; ++p) {
        int idx = p * 512 + t;            // 16B chunk id, 0..2047
        int row = idx >> 4, ch = idx & 15;
        int sc  = ch ^ (row & 7);
        uint4 va = ((const uint4*)Ag)[idx];
        uint4 vb = ((const uint4*)Bg)[idx];
        *(uint4*)&As[row * 128 + sc * 8] = va;
        *(uint4*)&Bs[row * 128 + sc * 8] = vb;
    }
    __syncthreads();

    const int wave = t >> 6, lane = t & 63;
    const int q = lane >> 4, c = lane & 15;
    const int wr = (wave >> 1) * 32;      // 0,32,64,96
    const int wc = (wave & 1) * 64;       // 0,64

    float4v acc[2][4] = {};
    #pragma unroll
    for (int kk = 0; kk < 4; ++kk) {
        short8v af[2], bfr[4];
        #pragma unroll
        for (int ti = 0; ti < 2; ++ti) {
            int row = wr + ti * 16 + c;
            int sc  = (kk * 4 + q) ^ (row & 7);
            af[ti] = *(const short8v*)&As[row * 128 + sc * 8];
        }
        #pragma unroll
        for (int tj = 0; tj < 4; ++tj) {
            int row = wc + tj * 16 + c;
            int sc  = (kk * 4 + q) ^ (row & 7);
            bfr[tj] = *(const short8v*)&Bs[row * 128 + sc * 8];
        }
        #pragma unroll
        for (int ti = 0; ti < 2; ++ti)
            #pragma unroll
            for (int tj = 0; tj < 4; ++tj)
                acc[ti][tj] = __builtin_amdgcn_mfma_f32_16x16x32_bf16(
                    af[ti], bfr[tj], acc[ti][tj], 0, 0, 0);
    }

    // ---- epilogue: C layout col = lane&15 (=c), row = q*4 + reg
    const float NEG_INF = __int_as_float((int)0xFF800000u);
    const float POS_INF = __int_as_float(0x7F800000);

    const int aMin = labs[bm * 128], aMax = labs[bm * 128 + 127];
    const int bMn  = labs[HALF + bn * 128], bMx = labs[HALF + bn * 128 + 127];
    const bool overlap = (aMax >= bMn) && (bMx >= aMin);   // block-uniform

    float sA[8];
    #pragma unroll
    for (int ti = 0; ti < 2; ++ti)
        #pragma unroll
        for (int reg = 0; reg < 4; ++reg)
            sA[ti * 4 + reg] = sq[bm * 128 + wr + ti * 16 + q * 4 + reg];
    float sB[4];
    #pragma unroll
    for (int tj = 0; tj < 4; ++tj)
        sB[tj] = sq[HALF + bn * 128 + wc + tj * 16 + c];

    float rmin[8], cmin[4];
    #pragma unroll
    for (int i = 0; i < 8; ++i) rmin[i] = POS_INF;
    #pragma unroll
    for (int j = 0; j < 4; ++j) cmin[j] = POS_INF;

    if (!overlap) {
        // ---- fast path: every pair is a negative
        #pragma unroll
        for (int ti = 0; ti < 2; ++ti)
            #pragma unroll
            for (int tj = 0; tj < 4; ++tj)
                #pragma unroll
                for (int reg = 0; reg < 4; ++reg) {
                    int ri = ti * 4 + reg;
                    float d2 = fmaf(acc[ti][tj][reg], -2.0f, sA[ri] + sB[tj]);
                    rmin[ri] = fminf(rmin[ri], d2);
                    cmin[tj] = fminf(cmin[tj], d2);
                }
        #pragma unroll
        for (int m = 1; m <= 8; m <<= 1)
            #pragma unroll
            for (int i = 0; i < 8; ++i)
                rmin[i] = fminf(rmin[i], __shfl_xor(rmin[i], m, 64));
        if (c == 0) {
            #pragma unroll
            for (int ti = 0; ti < 2; ++ti)
                #pragma unroll
                for (int reg = 0; reg < 4; ++reg)
                    atomicMin(&minneg[bm * 128 + wr + ti * 16 + q * 4 + reg],
                              __float_as_int(rmin[ti * 4 + reg]));
        }
        #pragma unroll
        for (int m = 16; m <= 32; m <<= 1)
            #pragma unroll
            for (int j = 0; j < 4; ++j)
                cmin[j] = fminf(cmin[j], __shfl_xor(cmin[j], m, 64));
        if (q == 0) {
            #pragma unroll
            for (int tj = 0; tj < 4; ++tj)
                atomicMin(&minneg[HALF + bn * 128 + wc + tj * 16 + c],
                          __float_as_int(cmin[tj]));
        }
    } else {
        // ---- slow path: labels may match
        float rmax[8], cmax[4];
        #pragma unroll
        for (int i = 0; i < 8; ++i) rmax[i] = NEG_INF;
        #pragma unroll
        for (int j = 0; j < 4; ++j) cmax[j] = NEG_INF;

        int tA[8];
        #pragma unroll
        for (int ti = 0; ti < 2; ++ti)
            #pragma unroll
            for (int reg = 0; reg < 4; ++reg)
                tA[ti * 4 + reg] = labs[bm * 128 + wr + ti * 16 + q * 4 + reg];
        int tB[4];
        #pragma unroll
        for (int tj = 0; tj < 4; ++tj)
            tB[tj] = labs[HALF + bn * 128 + wc + tj * 16 + c];

        #pragma unroll
        for (int ti = 0; ti < 2; ++ti)
            #pragma unroll
            for (int tj = 0; tj < 4; ++tj) {
                #pragma unroll
                for (int reg = 0; reg < 4; ++reg) {
                    int ri = ti * 4 + reg;
                    float d2 = fmaf(acc[ti][tj][reg], -2.0f, sA[ri] + sB[tj]);
                    bool same = (tA[ri] == tB[tj]);
                    float posc = same ? d2 : NEG_INF;
                    float negc = same ? POS_INF : d2;
                    rmax[ri] = fmaxf(rmax[ri], posc);
                    cmax[tj] = fmaxf(cmax[tj], posc);
                    rmin[ri] = fminf(rmin[ri], negc);
                    cmin[tj] = fminf(cmin[tj], negc);
                }
            }
        #pragma unroll
        for (int m = 1; m <= 8; m <<= 1)
            #pragma unroll
            for (int i = 0; i < 8; ++i) {
                rmax[i] = fmaxf(rmax[i], __shfl_xor(rmax[i], m, 64));
                rmin[i] = fminf(rmin[i], __shfl_xor(rmin[i], m, 64));
            }
        if (c == 0) {
            #pragma unroll
            for (int ti = 0; ti < 2; ++ti)
                #pragma unroll
                for (int reg = 0; reg < 4; ++reg) {
                    int gi = bm * 128 + wr + ti * 16 + q * 4 + reg;
                    atomicMax(&maxpos[gi], __float_as_int(rmax[ti * 4 + reg]));
                    atomicMin(&minneg[gi], __float_as_int(rmin[ti * 4 + reg]));
                }
        }
        #pragma unroll
        for (int m = 16; m <= 32; m <<= 1)
            #pragma unroll
            for (int j = 0; j < 4; ++j) {
                cmax[j] = fmaxf(cmax[j], __shfl_xor(cmax[j], m, 64));
                cmin[j] = fminf(cmin[j], __shfl_xor(cmin[j], m, 64));
            }
        if (q == 0) {
            #pragma unroll
            for (int tj = 0; tj < 4; ++tj) {
                int gj = HALF + bn * 128 + wc + tj * 16 + c;
                atomicMax(&maxpos[gj], __float_as_int(cmax[tj]));
                atomicMin(&minneg[gj], __float_as_int(cmin[tj]));
            }
        }
    }
}

// ---------------------------------------------------------------------------
// final: per-row loss terms -> global accumulators; LAST block (ticket)
// writes d_out. (write_kernel fused in.)
// ---------------------------------------------------------------------------
__global__ __launch_bounds__(256) void final_kernel(
        const int* __restrict__ maxpos, const int* __restrict__ minneg,
        int* __restrict__ accs /* [accF, accI, ticket] */,
        float* __restrict__ out) {
    const int i = blockIdx.x * 256 + threadIdx.x;  // 64 blocks x 256 = 16384
    const int t = threadIdx.x;
    float* accF  = (float*)&accs[0];
    int*   accI  = &accs[1];
    int*   tick  = &accs[2];
    float ap = sqrtf(fmaxf(__int_as_float(maxpos[i]), 1e-12f));
    float an = sqrtf(fmaxf(__int_as_float(minneg[i]), 1e-12f));
    float term = fmaxf(ap - an + MARGIN, 0.0f);
    int cnt = (an >= ap) ? 1 : 0;
    #pragma unroll
    for (int m = 1; m < 64; m <<= 1) {
        term += __shfl_xor(term, m, 64);
        cnt  += __shfl_xor(cnt, m, 64);
    }
    __shared__ float sf[4];
    __shared__ int   si[4];
    if ((t & 63) == 0) { sf[t >> 6] = term; si[t >> 6] = cnt; }
    __syncthreads();
    if (t == 0) {
        atomicAdd(accF, sf[0] + sf[1] + sf[2] + sf[3]);
        atomicAdd(accI, si[0] + si[1] + si[2] + si[3]);
        __threadfence();
        int old = atomicAdd(tick, 1);
        if (old == gridDim.x - 1) {                // last block: all adds visible
            __threadfence();
            float S = atomicAdd(accF, 0.0f);
            int   C = atomicAdd(accI, 0);
            out[0] = S / (float)N_TOTAL;
            out[1] = (float)C;
        }
    }
}

extern "C" void kernel_launch(void* const* d_in, const int* in_sizes, int n_in,
                              void* d_out, int out_size, void* d_ws, size_t ws_size,
                              hipStream_t stream) {
    const float* X       = (const float*)d_in[0];   // [16384,128] fp32
    const int*   targets = (const int*)d_in[1];     // [16384] int32
    float* out = (float*)d_out;                     // [2]: loss, correct

    char* ws = (char*)d_ws;
    const size_t XB_BYTES = (size_t)N_TOTAL * FEAT * 2;              // 4 MB
    unsigned* Xb  = (unsigned*)ws;
    float* sq     = (float*)(ws + XB_BYTES);                         // 64 KB
    int* maxpos   = (int*)(ws + XB_BYTES + 1 * 65536);               // 64 KB
    int* minneg   = (int*)(ws + XB_BYTES + 2 * 65536);               // 64 KB
    int* labs     = (int*)(ws + XB_BYTES + 3 * 65536);               // 64 KB
    int* cursor   = (int*)(ws + XB_BYTES + 4 * 65536);               // 8 KB (2x1024)
    int* accs     = cursor + 2 * NBINS;                              // 12 B

    sort_init_kernel<<<1, 1024, 0, stream>>>(targets, cursor, accs);
    prep_kernel     <<<4096, 256, 0, stream>>>(X, targets, cursor, Xb, sq, labs,
                                               maxpos, minneg);
    cross_kernel    <<<dim3(64, 64), 512, 0, stream>>>(
        (const unsigned short*)Xb, sq, labs, maxpos, minneg);
    final_kernel    <<<64, 256, 0, stream>>>(maxpos, minneg, accs, out);
}